// Round 8
// baseline (173.840 us; speedup 1.0000x reference)
//
#include <hip/hip_runtime.h>
#include <hip/hip_bf16.h>
#include <stdint.h>

#define SCALE 0.25f

typedef __attribute__((ext_vector_type(8))) short bf16x8;
typedef __attribute__((ext_vector_type(4))) float f32x4;
typedef __attribute__((ext_vector_type(16))) float f32x16;
typedef _Float16 h2 __attribute__((ext_vector_type(2)));
typedef unsigned int u32;

static __device__ __forceinline__ float fdot2f(u32 a, u32 b, float c) {
#if __has_builtin(__builtin_amdgcn_fdot2)
    return __builtin_amdgcn_fdot2(__builtin_bit_cast(h2, a), __builtin_bit_cast(h2, b), c, false);
#else
    h2 ha = __builtin_bit_cast(h2, a), hb = __builtin_bit_cast(h2, b);
    return c + (float)ha[0] * (float)hb[0] + (float)ha[1] * (float)hb[1];
#endif
}
static __device__ __forceinline__ float lo16f(u32 u) { return (float)__builtin_bit_cast(h2, u)[0]; }
static __device__ __forceinline__ float hi16f(u32 u) { return (float)__builtin_bit_cast(h2, u)[1]; }

// ---------------------------------------------------------------- W repack
// W[o][i][t] (15 f32) -> W3[o][12 dwords]: 9 f16-pair dwords {(w0,w1),(w2,w3),(w4,0)} x3 i,
// slot 9 = bias f32, 10/11 pad. Row = 48 B (b128-aligned).
__global__ __launch_bounds__(256) void prep_w3_kernel(const float* __restrict__ W,
                                                      const float* __restrict__ bias,
                                                      u32* __restrict__ W3) {
    int idx = blockIdx.x * 256 + threadIdx.x;
    if (idx >= 24576 * 12) return;
    int o = idx / 12, s = idx - o * 12;
    u32 val = 0;
    if (s < 9) {
        int i = s / 3, pp = s - i * 3;
        float w0 = W[o * 15 + i * 5 + 2 * pp];
        float w1 = (2 * pp + 1 < 5) ? W[o * 15 + i * 5 + 2 * pp + 1] : 0.f;
        h2 pk; pk[0] = (_Float16)w0; pk[1] = (_Float16)w1;
        val = __builtin_bit_cast(u32, pk);
    } else if (s == 9) {
        val = __builtin_bit_cast(u32, bias[o]);
    }
    W3[idx] = val;
}

// ---------------------------------------------------------------- fused kernel
// block = (bk, 32 s), 512 thr (8 waves), 2 blocks/CU target.
// s-INTERLEAVED stages: conv quarter qs produces s = 4j+qs (j=0..7 slots);
// attn stage (h,q): wave wid does s = 4*wid+q -> xo f32x4 regs over q -> direct
// float4 global stores at q==3 (no xo LDS, no sweep). attn-mean in packed f16x2.
//
// LDS (dynamic, 80640 B -> 2 blocks/CU):
//   qk0 @0     : [8 j][2][512] bf16   16384
//   qk1 @16384 :                      16384
//   vt0 @32768 : [8 j][16 dk][40] bf16 10240
//   vt1 @43008 :                      10240
//   pT  @53248 : [8 w][32][40] ushort 20480
//   xs  @73728 : [96][36] f16          6912
//   att @0     : [512][36] f32 overlay after main loop
#define QK0_OFF 0
#define QK1_OFF 16384
#define VT0_OFF 32768
#define VT1_OFF 43008
#define PT_OFF  53248
#define XS_OFF  73728
#define LDS_TOTAL 80640

__global__ __launch_bounds__(512, 4) void fused5_kernel(const float* __restrict__ x,
                                                        const u32* __restrict__ W3,
                                                        float* __restrict__ out,
                                                        float* __restrict__ out_am) {
    extern __shared__ char smraw[];
    _Float16* xs = (_Float16*)(smraw + XS_OFF);
    unsigned short* pT = (unsigned short*)(smraw + PT_OFF);
    float* att = (float*)smraw;

    // XCD-aware decode
    int bi = blockIdx.x, slot = bi & 7, jj2 = bi >> 3;
    int k_ = slot >> 1, b = jj2 >> 4, st = ((slot & 1) << 4) | (jj2 & 15);
    int bk = b * 4 + k_;

    int t = threadIdx.x;
    int wid = t >> 6, lane = t & 63;
    int l31 = lane & 31, hi2 = lane >> 5;
    int l15 = lane & 15, hi4 = lane >> 4;
    int v = t >> 4, dk = t & 15;
    int g3 = (k_ * 32 + v) * 3;

    u32 WE[3][9]; float bs[3];
    auto loadw = [&](int hh) {
        #pragma unroll
        for (int c3 = 0; c3 < 3; ++c3) {
            const uint4* p = (const uint4*)(W3 + (size_t)((g3 + c3) * 64 + hh * 16 + dk) * 12);
            uint4 A = p[0], B4 = p[1], C4 = p[2];
            WE[c3][0] = A.x;  WE[c3][1] = A.y;  WE[c3][2] = A.z;  WE[c3][3] = A.w;
            WE[c3][4] = B4.x; WE[c3][5] = B4.y; WE[c3][6] = B4.z; WE[c3][7] = B4.w;
            WE[c3][8] = C4.x; bs[c3] = __builtin_bit_cast(float, C4.y);
        }
    };

    // conv for interleaved quarter qs (s = 4j + qs): dword f16 loads, dot2 taps.
    auto conv_stage = [&](int qs, int bufi) {
        __hip_bfloat16* qkw = (__hip_bfloat16*)(smraw + (bufi ? QK1_OFF : QK0_OFF));
        __hip_bfloat16* vtw = (__hip_bfloat16*)(smraw + (bufi ? VT1_OFF : VT0_OFF));
        const int PI_ = qs & 1;
        #pragma unroll
        for (int hb = 0; hb < 2; ++hb) {
            float acc0[4], acc1[4], acc2[4];
            #pragma unroll
            for (int j4 = 0; j4 < 4; ++j4) { acc0[j4] = bs[0]; acc1[j4] = bs[1]; acc2[j4] = bs[2]; }
            #pragma unroll
            for (int ii = 0; ii < 3; ++ii) {
                const u32* xrow = (const u32*)xs + (v * 3 + ii) * 18 + 8 * hb + ((qs - PI_) >> 1);
                u32 Dv[9];
                #pragma unroll
                for (int d = 0; d < 9; ++d) Dv[d] = xrow[d];
                u32 wp0[3], wp1[3]; float wsc[3];
                #pragma unroll
                for (int c3 = 0; c3 < 3; ++c3) {
                    if (PI_) {
                        wp0[c3] = __builtin_amdgcn_alignbit(WE[c3][ii * 3 + 1], WE[c3][ii * 3 + 0], 16);
                        wp1[c3] = __builtin_amdgcn_alignbit(WE[c3][ii * 3 + 2], WE[c3][ii * 3 + 1], 16);
                        wsc[c3] = lo16f(WE[c3][ii * 3 + 0]);
                    } else {
                        wp0[c3] = WE[c3][ii * 3 + 0];
                        wp1[c3] = WE[c3][ii * 3 + 1];
                        wsc[c3] = lo16f(WE[c3][ii * 3 + 2]);
                    }
                }
                #pragma unroll
                for (int j4 = 0; j4 < 4; ++j4) {
                    u32 pa = Dv[2 * j4 + PI_], pb = Dv[2 * j4 + 1 + PI_];
                    float xsc = PI_ ? hi16f(Dv[2 * j4]) : lo16f(Dv[2 * j4 + 2]);
                    acc0[j4] = fdot2f(wp0[0], pa, acc0[j4]);
                    acc0[j4] = fdot2f(wp1[0], pb, acc0[j4]);
                    acc0[j4] = fmaf(wsc[0], xsc, acc0[j4]);
                    acc1[j4] = fdot2f(wp0[1], pa, acc1[j4]);
                    acc1[j4] = fdot2f(wp1[1], pb, acc1[j4]);
                    acc1[j4] = fmaf(wsc[1], xsc, acc1[j4]);
                    acc2[j4] = fdot2f(wp0[2], pa, acc2[j4]);
                    acc2[j4] = fdot2f(wp1[2], pb, acc2[j4]);
                    acc2[j4] = fmaf(wsc[2], xsc, acc2[j4]);
                }
            }
            #pragma unroll
            for (int j4 = 0; j4 < 4; ++j4) {
                int j_ = hb * 4 + j4;
                qkw[(j_ * 2 + 0) * 512 + v * 16 + dk] = __float2bfloat16(acc0[j4]);
                qkw[(j_ * 2 + 1) * 512 + v * 16 + dk] = __float2bfloat16(acc1[j4]);
                vtw[(j_ * 16 + dk) * 40 + v] = __float2bfloat16(acc2[j4]);
            }
        }
    };

    h2 quart; quart[0] = (_Float16)0.25f; quart[1] = (_Float16)0.25f;
    h2 accQ[4][8];
    #pragma unroll
    for (int a = 0; a < 4; ++a)
        #pragma unroll
        for (int m = 0; m < 8; ++m) { accQ[a][m][0] = (_Float16)0.f; accQ[a][m][1] = (_Float16)0.f; }
    f32x4 xo_acc[4][2];

    // ---- x window [96 ch][36 s] -> LDS f16
    loadw(0);
    {
        int sbase = st * 32 - 4;
        #pragma unroll
        for (int i = 0; i < 7; ++i) {
            int idx = i * 512 + t;
            if (idx < 3456) {
                int row = idx / 36, col = idx - row * 36;
                int sg = sbase + col;
                float val = (sg >= 0) ? x[((size_t)b * 384 + k_ * 96 + row) * 1024 + sg] : 0.f;
                xs[idx] = (_Float16)val;
            }
        }
    }
    __syncthreads();
    conv_stage(0, 0);
    __syncthreads();

    for (int h = 0; h < 4; ++h) {
        #pragma unroll
        for (int q = 0; q < 4; ++q) {
            if (q == 3 && h < 3) loadw(h + 1);

            // ---------------- attn(h,q): s = 4*wid + q, reads qk/vt[q&1]
            {
                const __hip_bfloat16* qk =
                    (const __hip_bfloat16*)(smraw + ((q & 1) ? QK1_OFF : QK0_OFF));
                const __hip_bfloat16* vt =
                    (const __hip_bfloat16*)(smraw + ((q & 1) ? VT1_OFF : VT0_OFF));
                const __hip_bfloat16* qb = qk + (wid * 2) * 512 + l31 * 16 + hi2 * 8;
                bf16x8 qf = *(const bf16x8*)qb;
                bf16x8 kf = *(const bf16x8*)(qb + 512);

                f32x16 zc;
                #pragma unroll
                for (int i = 0; i < 16; ++i) zc[i] = 0.f;
                f32x16 lg = __builtin_amdgcn_mfma_f32_32x32x16_bf16(kf, qf, zc, 0, 0, 0);

                float p[16], m = -3.0e38f;
                #pragma unroll
                for (int r = 0; r < 16; ++r) { p[r] = lg[r] * SCALE; m = fmaxf(m, p[r]); }
                m = fmaxf(m, __shfl_xor(m, 32));
                float ssum = 0.f;
                #pragma unroll
                for (int r = 0; r < 16; ++r) { p[r] = __expf(p[r] - m); ssum += p[r]; }
                ssum += __shfl_xor(ssum, 32);
                float inv = 1.f / ssum;
                #pragma unroll
                for (int r = 0; r < 16; ++r) p[r] *= inv;

                // pT pack (swizzled) + f16x2 attn-mean accumulate (pre-scaled /4)
                unsigned* pTrow = (unsigned*)(pT + (size_t)(wid * 32 + l31) * 40);
                int wsw = (l31 >> 3) & 1 ? 4 : 0;
                #pragma unroll
                for (int mm = 0; mm < 8; ++mm) {
                    unsigned pk;
                    asm("v_cvt_pk_bf16_f32 %0, %1, %2"
                        : "=v"(pk) : "v"(p[2 * mm]), "v"(p[2 * mm + 1]));
                    pTrow[((mm & 1) + 4 * (mm >> 1) + 2 * hi2) ^ wsw] = pk;
                    h2 pk2 = __builtin_bit_cast(h2, __builtin_amdgcn_cvt_pkrtz(p[2 * mm], p[2 * mm + 1]));
                    accQ[q][mm] += pk2 * quart;
                }

                int rsw = (l15 >> 3) & 1 ? 8 : 0;
                bf16x8 vf = *(const bf16x8*)((const unsigned short*)(vt) + (wid * 16 + l15) * 40 + hi4 * 8);
                bf16x8 p1 = *(const bf16x8*)&pT[(wid * 32 + l15) * 40 + (hi4 * 8 ^ rsw)];
                bf16x8 p2 = *(const bf16x8*)&pT[(wid * 32 + 16 + l15) * 40 + (hi4 * 8 ^ rsw)];
                f32x4 z4;
                #pragma unroll
                for (int i = 0; i < 4; ++i) z4[i] = 0.f;
                xo_acc[q][0] = __builtin_amdgcn_mfma_f32_16x16x32_bf16(vf, p1, z4, 0, 0, 0);
                xo_acc[q][1] = __builtin_amdgcn_mfma_f32_16x16x32_bf16(vf, p2, z4, 0, 0, 0);

                if (q == 3) {   // direct f4-along-s stores for s = 4wid..4wid+3
                    size_t sb = (size_t)st * 32 + 4 * wid;
                    #pragma unroll
                    for (int fr = 0; fr < 2; ++fr) {
                        int qv = fr * 16 + l15;
                        float* cb = out + ((size_t)b * 8192 + k_ * 2048 + qv * 64 + h * 16 + hi4 * 4) * 1024 + sb;
                        #pragma unroll
                        for (int r = 0; r < 4; ++r) {
                            float4 o4;
                            o4.x = xo_acc[0][fr][r]; o4.y = xo_acc[1][fr][r];
                            o4.z = xo_acc[2][fr][r]; o4.w = xo_acc[3][fr][r];
                            *(float4*)(cb + (size_t)r * 1024) = o4;
                        }
                    }
                }
            }

            // ---------------- conv(next quarter) -> buffers[(q+1)&1]
            if (!(h == 3 && q == 3)) {
                conv_stage((q + 1) & 3, (q + 1) & 1);
            }
            __syncthreads();
        }
    }

    // ---------------- attn-mean epilogue: att[512][36] overlay, 2 passes
    #pragma unroll
    for (int pass = 0; pass < 2; ++pass) {
        if (pass) __syncthreads();
        if ((l31 >> 4) == pass) {
            int qh = l31 & 15;
            int csw = 4 * (qh & 7);
            #pragma unroll
            for (int q = 0; q < 4; ++q) {
                int sp = 4 * wid + q;
                int colp = sp ^ csw;
                #pragma unroll
                for (int mm = 0; mm < 8; ++mm) {
                    int kv = ((2 * mm) & 3) + 8 * (mm >> 1) + 4 * hi2;
                    att[(qh * 32 + kv) * 36 + colp] = (float)accQ[q][mm][0];
                    att[(qh * 32 + kv + 1) * 36 + colp] = (float)accQ[q][mm][1];
                }
            }
        }
        __syncthreads();
        #pragma unroll
        for (int j = 0; j < 8; ++j) {
            int tr = j * 64 + (t >> 3);
            int csw = 4 * ((tr >> 5) & 7);
            int s4 = (t & 7) * 4;
            float4 o;
            o.x = att[tr * 36 + ((s4 + 0) ^ csw)];
            o.y = att[tr * 36 + ((s4 + 1) ^ csw)];
            o.z = att[tr * 36 + ((s4 + 2) ^ csw)];
            o.w = att[tr * 36 + ((s4 + 3) ^ csw)];
            *(float4*)(out_am + ((size_t)bk * 1024 + pass * 512 + tr) * 1024 + st * 32 + s4) = o;
        }
    }
}

// ---------------------------------------------------------------- launch
extern "C" void kernel_launch(void* const* d_in, const int* in_sizes, int n_in,
                              void* d_out, int out_size, void* d_ws, size_t ws_size,
                              hipStream_t stream) {
    const float* x = (const float*)d_in[0];
    const float* W = (const float*)d_in[1];
    const float* bias = (const float*)d_in[2];
    float* out = (float*)d_out;
    float* out_am = out + (size_t)33554432;   // xo is 4*8192*1024

    u32* W3 = (u32*)d_ws;                     // 24576*12*4 = 1.18 MB

    (void)hipFuncSetAttribute((const void*)fused5_kernel,
                              hipFuncAttributeMaxDynamicSharedMemorySize, LDS_TOTAL);

    prep_w3_kernel<<<1152, 256, 0, stream>>>(W, bias, W3);
    fused5_kernel<<<512, 512, LDS_TOTAL, stream>>>(x, W3, out, out_am);
}

// Round 11
// 123.175 us; speedup vs baseline: 1.4113x; 1.4113x over previous
//
#include <hip/hip_runtime.h>
#include <hip/hip_bf16.h>
#include <stdint.h>

#define SCALE 0.25f

typedef __attribute__((ext_vector_type(8))) short bf16x8;
typedef __attribute__((ext_vector_type(4))) float f32x4;
typedef __attribute__((ext_vector_type(16))) float f32x16;
typedef __fp16 fp16x4 __attribute__((ext_vector_type(4)));
typedef unsigned int u32;
typedef unsigned short u16;

// ---------------------------------------------------------------- Wb prep (bf16)
// Wb[k_][v][h][c3][dk][k=32] bf16: k<15 -> W[o*15+k]; k==15 -> bias[o]; else 0.
// (o = ((k_*32+v)*3+c3)*64 + h*16 + dkq). A-frag row = dk, k-chunk = hi4*8.
__global__ __launch_bounds__(256) void prep_wb_kernel(const float* __restrict__ W,
                                                      const float* __restrict__ bias,
                                                      __hip_bfloat16* __restrict__ Wb) {
    int idx = blockIdx.x * 256 + threadIdx.x;
    if (idx >= 786432) return;
    int k = idx & 31; int r = idx >> 5;
    int dkq = r & 15; r >>= 4;
    int c3 = r % 3; r /= 3;
    int h = r & 3; r >>= 2;
    int v = r & 31; int kq = r >> 5;
    int o = ((kq * 32 + v) * 3 + c3) * 64 + h * 16 + dkq;
    float val = 0.f;
    if (k < 15) val = W[o * 15 + k];
    else if (k == 15) val = bias[o];
    Wb[idx] = __float2bfloat16(val);
}

// ---------------------------------------------------------------- fused kernel
// block = (bk, 32 s), 512 thr (8 waves). 8 stages (h, half-of-16-s):
//   { conv-MFMA(bf16) -> qk/vT ; barrier ; attn (2 s/wave) -> ring ;
//     (half==0: sweep(h-1)) ; barrier }
// conv: per v, D[48 o][16 s] = Wb-frags x im2col(xs)-frags, bias via k=15 column.
// ALL MFMA are the hardware-proven bf16 variants; all LDS layouts R6-verified.
//
// LDS (dynamic, 132096 B):
//   qk  @0      : [16 s][2][536] bf16   34304
//   vT  @34304  : [256][40] bf16        20480
//   pT  @54784  : [8 w][32][40] ushort  20480
//   xs  @75264  : [96][36] bf16          6912
//   ring@82176  : [48][520] f16         49920
//   att @0      : [512][36] f32 overlay after main loop (73728 < 75264: xs/ring safe)
#define QK_OFF   0
#define VT_OFF   34304
#define PT_OFF   54784
#define XS_OFF   75264
#define RING_OFF 82176
#define LDS_TOTAL 132096
#define QKSTRIDE 536

__global__ __launch_bounds__(512) void fused8_kernel(const float* __restrict__ x,
                                                     const __hip_bfloat16* __restrict__ Wb,
                                                     float* __restrict__ out,
                                                     float* __restrict__ out_am) {
    extern __shared__ char smraw[];
    __hip_bfloat16* qk = (__hip_bfloat16*)(smraw + QK_OFF);
    __hip_bfloat16* vt = (__hip_bfloat16*)(smraw + VT_OFF);
    unsigned short* pT = (unsigned short*)(smraw + PT_OFF);
    u16* xs = (u16*)(smraw + XS_OFF);          // bf16 bits
    __fp16* ring = (__fp16*)(smraw + RING_OFF);
    float* att = (float*)smraw;

    // XCD-aware decode: same-k_ blocks share 2 XCD slots -> Wb slice L2-resident
    int bi = blockIdx.x, slot = bi & 7, jj2 = bi >> 3;
    int k_ = slot >> 1, b = jj2 >> 4, st = ((slot & 1) << 4) | (jj2 & 15);
    int bk = b * 4 + k_;

    int t = threadIdx.x;
    int wid = t >> 6, lane = t & 63;
    int l31 = lane & 31, hi2 = lane >> 5;
    int l15 = lane & 15, hi4 = lane >> 4;

    float acc_am[4][16];
    #pragma unroll
    for (int a = 0; a < 4; ++a)
        #pragma unroll
        for (int r = 0; r < 16; ++r) acc_am[a][r] = 0.f;

    // ---- x window [96 ch][36 s] -> LDS bf16 (once)
    {
        int sbase = st * 32 - 4;
        #pragma unroll
        for (int i = 0; i < 7; ++i) {
            int idx = i * 512 + t;
            if (idx < 3456) {
                int row = idx / 36, col = idx - row * 36;
                int sg = sbase + col;
                float val = (sg >= 0) ? x[((size_t)b * 384 + k_ * 96 + row) * 1024 + sg] : 0.f;
                __hip_bfloat16 bv = __float2bfloat16(val);
                xs[idx] = *(u16*)&bv;
            }
        }
    }
    __syncthreads();

    // full-line sweep of head hp: ring rows (32*hp..+31)%48 -> complete 128-B lines
    auto sweep = [&](int hp) {
        int rb = (32 * hp) % 48;
        int u = t >> 3, s4 = (t & 7) * 4;
        #pragma unroll
        for (int j = 0; j < 8; ++j) {
            int c_loc = j * 64 + u;
            float4 o;
            #pragma unroll
            for (int i2 = 0; i2 < 4; ++i2) {
                int rr = rb + s4 + i2; if (rr >= 48) rr -= 48;
                (&o.x)[i2] = (float)ring[rr * 520 + c_loc];
            }
            int c = k_ * 2048 + (c_loc >> 4) * 64 + hp * 16 + (c_loc & 15);
            *(float4*)(out + ((size_t)b * 8192 + c) * 1024 + st * 32 + s4) = o;
        }
    };

    f32x4 z4;
    #pragma unroll
    for (int i = 0; i < 4; ++i) z4[i] = 0.f;

    for (int h = 0; h < 4; ++h) {
        #pragma unroll
        for (int half = 0; half < 2; ++half) {
            // ================ conv-MFMA (bf16): wave covers v = wid*4..+3, 16 s
            #pragma unroll
            for (int vv = 0; vv < 4; ++vv) {
                int v = wid * 4 + vv;
                const __hip_bfloat16* wbase =
                    Wb + (size_t)((((k_ * 32 + v) * 4 + h) * 3) * 16) * 32;
                // A-frags (weights): row l15 = dk, k-chunk hi4*8 (32 bf16/row)
                bf16x8 wr0 = *(const bf16x8*)(wbase + (0 * 16 + l15) * 32 + hi4 * 8);
                bf16x8 wr1 = *(const bf16x8*)(wbase + (1 * 16 + l15) * 32 + hi4 * 8);
                bf16x8 wr2 = *(const bf16x8*)(wbase + (2 * 16 + l15) * 32 + hi4 * 8);
                // B-frag: im2col of xs, lane l15 = s col, k = hi4*8 + j (k=i*5+t; k15=bias 1.0)
                bf16x8 xf;
                #pragma unroll
                for (int j = 0; j < 8; ++j) xf[j] = 0;   // bf16 +0.0
                {
                    int cix = half * 16 + l15;
                    const u16* x0 = xs + (3 * v) * 36 + cix;
                    const u16* x1 = x0 + 36;
                    const u16* x2 = x0 + 72;
                    if (hi4 == 0) {
                        xf[0] = x0[0]; xf[1] = x0[1]; xf[2] = x0[2]; xf[3] = x0[3]; xf[4] = x0[4];
                        xf[5] = x1[0]; xf[6] = x1[1]; xf[7] = x1[2];
                    } else if (hi4 == 1) {
                        xf[0] = x1[3]; xf[1] = x1[4];
                        xf[2] = x2[0]; xf[3] = x2[1]; xf[4] = x2[2]; xf[5] = x2[3]; xf[6] = x2[4];
                        xf[7] = (short)0x3F80;           // bf16 1.0
                    }
                }
                f32x4 d0 = __builtin_amdgcn_mfma_f32_16x16x32_bf16(wr0, xf, z4, 0, 0, 0);
                f32x4 d1 = __builtin_amdgcn_mfma_f32_16x16x32_bf16(wr1, xf, z4, 0, 0, 0);
                f32x4 d2 = __builtin_amdgcn_mfma_f32_16x16x32_bf16(wr2, xf, z4, 0, 0, 0);

                // D: col(l15)=s, rows dk = 4*hi4+reg. Proven scalar bf16 stores.
                #pragma unroll
                for (int i2 = 0; i2 < 4; ++i2) {
                    int dk = 4 * hi4 + i2;
                    qk[(l15 * 2 + 0) * QKSTRIDE + v * 16 + dk] = __float2bfloat16(d0[i2]);
                    qk[(l15 * 2 + 1) * QKSTRIDE + v * 16 + dk] = __float2bfloat16(d1[i2]);
                    vt[(l15 * 16 + dk) * 40 + v] = __float2bfloat16(d2[i2]);
                }
            }
            __syncthreads();

            // ================ attn: 2 s per wave (s_tile = wid*2 + jj)
            #pragma unroll
            for (int jj = 0; jj < 2; ++jj) {
                int s_tile = wid * 2 + jj;
                const __hip_bfloat16* qb = qk + (s_tile * 2) * QKSTRIDE + l31 * 16 + hi2 * 8;
                bf16x8 qf = *(const bf16x8*)qb;
                bf16x8 kf = *(const bf16x8*)(qb + QKSTRIDE);

                f32x16 zc;
                #pragma unroll
                for (int i = 0; i < 16; ++i) zc[i] = 0.f;
                f32x16 lg = __builtin_amdgcn_mfma_f32_32x32x16_bf16(kf, qf, zc, 0, 0, 0);

                float p[16], m = -3.0e38f;
                #pragma unroll
                for (int r = 0; r < 16; ++r) { p[r] = lg[r] * SCALE; m = fmaxf(m, p[r]); }
                m = fmaxf(m, __shfl_xor(m, 32));
                float ssum = 0.f;
                #pragma unroll
                for (int r = 0; r < 16; ++r) { p[r] = __expf(p[r] - m); ssum += p[r]; }
                ssum += __shfl_xor(ssum, 32);
                float inv = 1.f / ssum;
                int a_idx = half * 2 + jj;
                #pragma unroll
                for (int r = 0; r < 16; ++r) { p[r] *= inv; acc_am[a_idx][r] += p[r]; }

                // pT [qv][kv] bf16, write-swizzled (R6 verbatim)
                unsigned* pTrow = (unsigned*)(pT + (size_t)(wid * 32 + l31) * 40);
                int wsw = (l31 >> 3) & 1 ? 4 : 0;
                #pragma unroll
                for (int mm = 0; mm < 8; ++mm) {
                    unsigned pk;
                    asm("v_cvt_pk_bf16_f32 %0, %1, %2"
                        : "=v"(pk) : "v"(p[2 * mm]), "v"(p[2 * mm + 1]));
                    pTrow[((mm & 1) + 4 * (mm >> 1) + 2 * hi2) ^ wsw] = pk;
                }

                int rsw = (l15 >> 3) & 1 ? 8 : 0;
                bf16x8 vf = *(const bf16x8*)(vt + (s_tile * 16 + l15) * 40 + hi4 * 8);
                bf16x8 p1 = *(const bf16x8*)&pT[(wid * 32 + l15) * 40 + (hi4 * 8 ^ rsw)];
                bf16x8 p2 = *(const bf16x8*)&pT[(wid * 32 + 16 + l15) * 40 + (hi4 * 8 ^ rsw)];
                f32x4 xo1 = __builtin_amdgcn_mfma_f32_16x16x32_bf16(vf, p1, z4, 0, 0, 0);
                f32x4 xo2 = __builtin_amdgcn_mfma_f32_16x16x32_bf16(vf, p2, z4, 0, 0, 0);

                // ring row (32h + half*16 + s_tile) % 48; f16 RNE, b64 stores
                int rr = (32 * h + half * 16 + s_tile) % 48;
                __fp16* rowp = ring + rr * 520;
                fp16x4 e1, e2;
                #pragma unroll
                for (int i2 = 0; i2 < 4; ++i2) {
                    e1[i2] = (__fp16)xo1[i2];
                    e2[i2] = (__fp16)xo2[i2];
                }
                *(fp16x4*)(rowp + l15 * 16 + hi4 * 4) = e1;
                *(fp16x4*)(rowp + (16 + l15) * 16 + hi4 * 4) = e2;
            }

            // full-line sweep of previous head overlaps attn of (h, half0)
            if (half == 0 && h > 0) sweep(h - 1);

            __syncthreads();
        }
    }
    sweep(3);

    // ---------------- attn-mean: att[512][36] overlay, 2 passes over qv halves
    #pragma unroll
    for (int pass = 0; pass < 2; ++pass) {
        if (pass) __syncthreads();
        if ((l31 >> 4) == pass) {
            int qh = l31 & 15;
            int csw = 4 * (qh & 7);
            #pragma unroll
            for (int a = 0; a < 4; ++a) {
                int sp = (a >> 1) * 16 + wid * 2 + (a & 1);
                int colp = sp ^ csw;
                #pragma unroll
                for (int r = 0; r < 16; ++r) {
                    int kv = (r & 3) + 8 * (r >> 2) + 4 * hi2;
                    att[(qh * 32 + kv) * 36 + colp] = 0.25f * acc_am[a][r];
                }
            }
        }
        __syncthreads();
        #pragma unroll
        for (int j = 0; j < 8; ++j) {
            int tr = j * 64 + (t >> 3);
            int csw = 4 * ((tr >> 5) & 7);
            int s4 = (t & 7) * 4;
            float4 o;
            o.x = att[tr * 36 + ((s4 + 0) ^ csw)];
            o.y = att[tr * 36 + ((s4 + 1) ^ csw)];
            o.z = att[tr * 36 + ((s4 + 2) ^ csw)];
            o.w = att[tr * 36 + ((s4 + 3) ^ csw)];
            *(float4*)(out_am + ((size_t)bk * 1024 + pass * 512 + tr) * 1024 + st * 32 + s4) = o;
        }
    }
}

// ---------------------------------------------------------------- launch
extern "C" void kernel_launch(void* const* d_in, const int* in_sizes, int n_in,
                              void* d_out, int out_size, void* d_ws, size_t ws_size,
                              hipStream_t stream) {
    const float* x = (const float*)d_in[0];
    const float* W = (const float*)d_in[1];
    const float* bias = (const float*)d_in[2];
    float* out = (float*)d_out;
    float* out_am = out + (size_t)33554432;   // xo is 4*8192*1024

    __hip_bfloat16* Wb = (__hip_bfloat16*)d_ws;   // 786432 * 2 B = 1.5 MB

    (void)hipFuncSetAttribute((const void*)fused8_kernel,
                              hipFuncAttributeMaxDynamicSharedMemorySize, LDS_TOTAL);

    prep_wb_kernel<<<3072, 256, 0, stream>>>(W, bias, Wb);
    fused8_kernel<<<512, 512, LDS_TOTAL, stream>>>(x, Wb, out, out_am);
}